// Round 1
// baseline (873.981 us; speedup 1.0000x reference)
//
#include <hip/hip_runtime.h>
#include <hip/hip_bf16.h>

#define DIMF 128
#define KNBR 32
#define NH 4
#define DH 32
#define RADIUS 0.3f
#define CAND_MAX 2048
#define NF_STRIDE 129  // pad 128 -> 129 words: breaks 32-bank power-of-2 conflicts

// ---------------- kernel 1: per-point squared norms ----------------
__global__ __launch_bounds__(256) void sq_kernel(const float* __restrict__ xyz,
                                                 float* __restrict__ sn, int N) {
    int n = blockIdx.x * 256 + threadIdx.x;
    if (n < N) {
        float x = xyz[3 * n], y = xyz[3 * n + 1], z = xyz[3 * n + 2];
        sn[n] = (x * x + y * y) + z * z;  // left-to-right like np.sum
    }
}

// ---------------- kernel 1b: gather center (x,y,z,|c|^2) ----------------
__global__ __launch_bounds__(256) void gather_kernel(const float* __restrict__ xyz,
                                                     const float* __restrict__ sn,
                                                     const int* __restrict__ idxc,
                                                     float4* __restrict__ cdata, int M) {
    int m = blockIdx.x * 256 + threadIdx.x;
    if (m < M) {
        int i = idxc[m];
        cdata[m] = make_float4(xyz[3 * i], xyz[3 * i + 1], xyz[3 * i + 2], sn[i]);
    }
}

// ---------------- kernel 2: per-center radius top-K (one block per center) ---
__global__ __launch_bounds__(256) void topk_kernel(const float* __restrict__ xyz,
                                                   const float* __restrict__ sn,
                                                   const float4* __restrict__ cdata,
                                                   int* __restrict__ nbr, int N) {
    int m = blockIdx.x, t = threadIdx.x;
    __shared__ unsigned long long cand[CAND_MAX];
    __shared__ int cnt;
    if (t == 0) cnt = 0;
    __syncthreads();
    float4 c = cdata[m];
    for (int n = t; n < N; n += 256) {
        float px = xyz[3 * n], py = xyz[3 * n + 1], pz = xyz[3 * n + 2];
        float dot = c.x * px + c.y * py + c.z * pz;
        float d2 = c.w + sn[n] - 2.0f * dot;               // (sc+sn) - 2*dot, like ref
        float dist = sqrtf(fmaxf(d2, 1e-12f));
        if (dist < RADIUS) {  // self-point has dist~1e-6 -> always a candidate
            int p = atomicAdd(&cnt, 1);
            if (p < CAND_MAX)
                cand[p] = (((unsigned long long)__float_as_uint(dist)) << 32) | (unsigned)n;
        }
    }
    __syncthreads();
    int C = cnt < CAND_MAX ? cnt : CAND_MAX;
    // wave 0 extracts the K smallest (dist, idx) pairs; packed-u64 min is
    // lexicographic (dist, then lowest idx) == stable lax.top_k tie order.
    if (t < 64) {
        volatile unsigned long long* vc = cand;
        for (int kit = 0; kit < KNBR; ++kit) {
            unsigned long long best = ~0ull;
            for (int i = t; i < C; i += 64) {
                unsigned long long v = vc[i];
                if (v < best) best = v;
            }
            for (int off = 32; off; off >>= 1) {
                unsigned long long o = __shfl_xor(best, off);
                if (o < best) best = o;
            }
            for (int i = t; i < C; i += 64)
                if (vc[i] == best) vc[i] = ~0ull;
            if (t == 0) nbr[m * KNBR + kit] = (best == ~0ull) ? -1 : (int)(best & 0xffffffffu);
        }
    }
}

// ---------------- kernel 3: attention + FFN per center (block=128) ----------
__global__ __launch_bounds__(128) void attn_ffn_kernel(
    const float* __restrict__ feats, const int* __restrict__ idxc,
    const int* __restrict__ nbr,
    const float* __restrict__ Wq, const float* __restrict__ Wk,
    const float* __restrict__ Wv, const float* __restrict__ Wo,
    const float* __restrict__ bo, const float* __restrict__ g1,
    const float* __restrict__ be1, const float* __restrict__ g2,
    const float* __restrict__ be2, const float* __restrict__ W1,
    const float* __restrict__ b1f, const float* __restrict__ W2,
    const float* __restrict__ b2f, float* __restrict__ cfin) {
    int m = blockIdx.x, t = threadIdx.x;
    __shared__ float cf[DIMF];
    __shared__ float nf[KNBR * NF_STRIDE];
    __shared__ float q[DIMF];
    __shared__ float qw[NH * DIMF];
    __shared__ float lg[NH * KNBR];
    __shared__ float wsm[NH * KNBR];
    __shared__ float validf[KNBR];
    __shared__ float pool[NH * DIMF];
    __shared__ float updin[DIMF];
    __shared__ float upd[DIMF];
    __shared__ float cf2[DIMF];
    __shared__ float h1[4 * DIMF];
    __shared__ float ffn[DIMF];

    int ic = idxc[m];
    cf[t] = feats[(long)ic * DIMF + t];
    for (int k = 0; k < KNBR; ++k) {
        int ni = nbr[m * KNBR + k];
        if (t == 0) validf[k] = (ni >= 0) ? 1.0f : 0.0f;
        nf[k * NF_STRIDE + t] = (ni >= 0) ? feats[(long)ni * DIMF + t] : 0.0f;
    }
    __syncthreads();

    // q = Wq @ cf, with 1/sqrt(DH) folded in
    {
        float a = 0.f;
        const float* w = Wq + (long)t * DIMF;
        for (int j = 0; j < DIMF; ++j) a += w[j] * cf[j];
        q[t] = a * 0.17677669529663687f;
    }
    __syncthreads();

    // qw[h][j] = sum_d q[h*32+d] * Wk[h*32+d][j]   (fold Wk into q: K x 128^2 -> 4 x 128 x 32)
    for (int r = 0; r < NH; ++r) {
        int h = r, j = t;
        float a = 0.f;
        for (int d = 0; d < DH; ++d) a += q[h * DH + d] * Wk[(long)(h * DH + d) * DIMF + j];
        qw[h * DIMF + j] = a;
    }
    __syncthreads();

    // logits[h][k] = qw[h] . nf[k]
    {
        int h = t >> 5, k = t & 31;
        float a = 0.f;
        for (int j = 0; j < DIMF; ++j) a += qw[h * DIMF + j] * nf[k * NF_STRIDE + j];
        lg[h * KNBR + k] = (validf[k] > 0.f) ? a : -1e9f;
    }
    __syncthreads();

    // softmax over k within each head (redundant per-lane loops; 32 elems)
    {
        int h = t >> 5, k = t & 31;
        float mx = -INFINITY;
        for (int kk = 0; kk < KNBR; ++kk) mx = fmaxf(mx, lg[h * KNBR + kk]);
        float s = 0.f;
        for (int kk = 0; kk < KNBR; ++kk) s += expf(lg[h * KNBR + kk] - mx);
        wsm[h * KNBR + k] = expf(lg[h * KNBR + k] - mx) / s;
    }
    __syncthreads();

    // pool[h][j] = sum_k w[h][k] * nf[k][j]
    for (int r = 0; r < NH; ++r) {
        int h = r, j = t;
        float a = 0.f;
        for (int k = 0; k < KNBR; ++k) a += wsm[h * KNBR + k] * nf[k * NF_STRIDE + j];
        pool[h * DIMF + j] = a;
    }
    __syncthreads();

    // attn_out[i=t] = Wv[i] . pool[h]; store into torch transpose(1,2) layout d*H+h
    {
        int h = t >> 5, d = t & 31;
        float a = 0.f;
        const float* w = Wv + (long)t * DIMF;
        for (int j = 0; j < DIMF; ++j) a += w[j] * pool[h * DIMF + j];
        updin[d * NH + h] = a;
    }
    __syncthreads();

    // upd = Wo @ updin + bo
    {
        float a = bo[t];
        const float* w = Wo + (long)t * DIMF;
        for (int j = 0; j < DIMF; ++j) a += w[j] * updin[j];
        upd[t] = a;
    }
    __syncthreads();

    // LN1 + residual
    {
        float mu = 0.f;
        for (int j = 0; j < DIMF; ++j) mu += upd[j];
        mu *= (1.0f / DIMF);
        float var = 0.f;
        for (int j = 0; j < DIMF; ++j) { float d = upd[j] - mu; var += d * d; }
        var *= (1.0f / DIMF);
        float ln = (upd[t] - mu) / sqrtf(var + 1e-5f) * g1[t] + be1[t];
        cf2[t] = cf[t] + ln;
    }
    __syncthreads();

    // FFN layer 1 (512 outputs, 4 per thread) + ReLU
    for (int r = 0; r < 4; ++r) {
        int u = r * DIMF + t;
        float a = b1f[u];
        const float* w = W1 + (long)u * DIMF;
        for (int j = 0; j < DIMF; ++j) a += w[j] * cf2[j];
        h1[u] = fmaxf(a, 0.f);
    }
    __syncthreads();

    // FFN layer 2
    {
        float a = b2f[t];
        const float* w = W2 + (long)t * (4 * DIMF);
        for (int u = 0; u < 4 * DIMF; ++u) a += w[u] * h1[u];
        ffn[t] = a;
    }
    __syncthreads();

    // LN2 + residual -> final center features
    {
        float mu = 0.f;
        for (int j = 0; j < DIMF; ++j) mu += ffn[j];
        mu *= (1.0f / DIMF);
        float var = 0.f;
        for (int j = 0; j < DIMF; ++j) { float d = ffn[j] - mu; var += d * d; }
        var *= (1.0f / DIMF);
        float ln = (ffn[t] - mu) / sqrtf(var + 1e-5f) * g2[t] + be2[t];
        cfin[(long)m * DIMF + t] = cf2[t] + ln;
    }
}

// ---------------- kernel 4: per-point nearest center (argmin, lowest-m ties) -
__global__ __launch_bounds__(256) void nearest_kernel(const float* __restrict__ xyz,
                                                      const float* __restrict__ sn,
                                                      const float4* __restrict__ cdata,
                                                      int* __restrict__ nearest, int N, int M) {
    __shared__ float4 cds[1024];
    int n = blockIdx.x * 256 + threadIdx.x;
    float px = 0.f, py = 0.f, pz = 0.f, psn = 0.f;
    if (n < N) { px = xyz[3 * n]; py = xyz[3 * n + 1]; pz = xyz[3 * n + 2]; psn = sn[n]; }
    float bestd = INFINITY;
    int bestm = 0;
    for (int t0 = 0; t0 < M; t0 += 1024) {
        int tile = (M - t0) < 1024 ? (M - t0) : 1024;
        __syncthreads();
        for (int i = threadIdx.x; i < tile; i += 256) cds[i] = cdata[t0 + i];
        __syncthreads();
        for (int i = 0; i < tile; ++i) {
            float4 c = cds[i];
            float dot = c.x * px + c.y * py + c.z * pz;
            float d2 = c.w + psn - 2.0f * dot;
            float dist = sqrtf(fmaxf(d2, 1e-12f));
            if (dist < bestd) { bestd = dist; bestm = t0 + i; }  // strict < : first-min = np.argmin
        }
    }
    if (n < N) nearest[n] = bestm;
}

// ---------------- kernel 5: out = feats + cfin[nearest] ----------------
__global__ __launch_bounds__(256) void out_kernel(const float4* __restrict__ feats4,
                                                  const float* __restrict__ cfin,
                                                  const int* __restrict__ nearest,
                                                  float4* __restrict__ out4, int total) {
    int idx = blockIdx.x * 256 + threadIdx.x;
    if (idx >= total) return;
    int n = idx >> 5, c = idx & 31;  // 32 float4 per 128-dim row
    const float4* cf4 = (const float4*)cfin;
    float4 f = feats4[idx];
    float4 g = cf4[(long)nearest[n] * 32 + c];
    out4[idx] = make_float4(f.x + g.x, f.y + g.y, f.z + g.z, f.w + g.w);
}

extern "C" void kernel_launch(void* const* d_in, const int* in_sizes, int n_in,
                              void* d_out, int out_size, void* d_ws, size_t ws_size,
                              hipStream_t stream) {
    const float* xyz = (const float*)d_in[0];
    const float* feats = (const float*)d_in[1];
    const int* idxc = (const int*)d_in[2];
    const float* Wq = (const float*)d_in[3];
    const float* Wk = (const float*)d_in[4];
    const float* Wv = (const float*)d_in[5];
    const float* Wo = (const float*)d_in[6];
    const float* bo = (const float*)d_in[7];
    const float* g1 = (const float*)d_in[8];
    const float* be1 = (const float*)d_in[9];
    const float* g2 = (const float*)d_in[10];
    const float* be2 = (const float*)d_in[11];
    const float* W1 = (const float*)d_in[12];
    const float* b1f = (const float*)d_in[13];
    const float* W2 = (const float*)d_in[14];
    const float* b2f = (const float*)d_in[15];

    int N = in_sizes[0] / 3;
    int M = in_sizes[2];

    // workspace carve (bytes, 16B-aligned chunks)
    char* ws = (char*)d_ws;
    float* sn = (float*)ws;                              // N floats
    size_t off = (size_t)N * 4;
    float4* cdata = (float4*)(ws + off);                 // M float4
    off += (size_t)M * 16;
    int* nbr = (int*)(ws + off);                         // M*K ints
    off += (size_t)M * KNBR * 4;
    float* cfin = (float*)(ws + off);                    // M*DIM floats
    off += (size_t)M * DIMF * 4;
    int* nearest = (int*)(ws + off);                     // N ints
    (void)ws_size; (void)n_in; (void)out_size;

    sq_kernel<<<(N + 255) / 256, 256, 0, stream>>>(xyz, sn, N);
    gather_kernel<<<(M + 255) / 256, 256, 0, stream>>>(xyz, sn, idxc, cdata, M);
    topk_kernel<<<M, 256, 0, stream>>>(xyz, sn, cdata, nbr, N);
    attn_ffn_kernel<<<M, 128, 0, stream>>>(feats, idxc, nbr, Wq, Wk, Wv, Wo, bo, g1, be1,
                                           g2, be2, W1, b1f, W2, b2f, cfin);
    nearest_kernel<<<(N + 255) / 256, 256, 0, stream>>>(xyz, sn, cdata, nearest, N, M);
    out_kernel<<<(N * DIMF / 4 + 255) / 256, 256, 0, stream>>>(
        (const float4*)feats, cfin, nearest, (float4*)d_out, N * DIMF / 4);
}

// Round 2
// 304.430 us; speedup vs baseline: 2.8709x; 2.8709x over previous
//
#include <hip/hip_runtime.h>
#include <hip/hip_bf16.h>

#define DIMF 128
#define KNBR 32
#define NH 4
#define DH 32
#define RADIUS 0.3f
#define CB 8       // centers per attn block
#define TC 4       // centers per topk block
#define CAND 1024
#define CT 512     // center tile in nearest

// ---------------- kernel 1: pack (x,y,z,|p|^2) ----------------
__global__ __launch_bounds__(256) void pdata_kernel(const float* __restrict__ xyz,
                                                    float4* __restrict__ pdata, int N) {
    int n = blockIdx.x * 256 + threadIdx.x;
    if (n < N) {
        float x = xyz[3 * n], y = xyz[3 * n + 1], z = xyz[3 * n + 2];
        pdata[n] = make_float4(x, y, z, (x * x + y * y) + z * z);
    }
}

// ---------------- kernel 1b: gather centers ----------------
__global__ __launch_bounds__(256) void gather_kernel(const float4* __restrict__ pdata,
                                                     const int* __restrict__ idxc,
                                                     float4* __restrict__ cdata, int M) {
    int m = blockIdx.x * 256 + threadIdx.x;
    if (m < M) cdata[m] = pdata[idxc[m]];
}

// ---------------- transpose: out[j*R+i] = in[i*C+j], grid=(C/32, R/32) ------
__global__ void transpose_kernel(const float* __restrict__ in, float* __restrict__ out,
                                 int R, int C) {
    __shared__ float tile[32][33];
    int bx = blockIdx.x * 32, by = blockIdx.y * 32;
    int tx = threadIdx.x, ty = threadIdx.y;
    for (int r = ty; r < 32; r += 8) {
        int row = by + r, col = bx + tx;
        tile[r][tx] = (row < R && col < C) ? in[(long)row * C + col] : 0.f;
    }
    __syncthreads();
    for (int r = ty; r < 32; r += 8) {
        int orow = bx + r, ocol = by + tx;  // out is C x R
        if (orow < C && ocol < R) out[(long)orow * R + ocol] = tile[tx][r];
    }
}

// ---------------- kernel 2: radius top-K, 4 centers per block ----------------
__global__ __launch_bounds__(256) void topk_kernel(const float4* __restrict__ pdata,
                                                   const float4* __restrict__ cdata,
                                                   int* __restrict__ nbr, int N) {
    __shared__ unsigned long long cand[TC][CAND];
    __shared__ int cnt[TC];
    int t = threadIdx.x;
    int m0 = blockIdx.x * TC;
    if (t < TC) cnt[t] = 0;
    __syncthreads();
    float4 c0 = cdata[m0 + 0], c1 = cdata[m0 + 1], c2 = cdata[m0 + 2], c3 = cdata[m0 + 3];
    for (int n = t; n < N; n += 256) {
        float4 p = pdata[n];
        float d0 = sqrtf(fmaxf(c0.w + p.w - 2.0f * (c0.x * p.x + c0.y * p.y + c0.z * p.z), 1e-12f));
        float d1 = sqrtf(fmaxf(c1.w + p.w - 2.0f * (c1.x * p.x + c1.y * p.y + c1.z * p.z), 1e-12f));
        float d2 = sqrtf(fmaxf(c2.w + p.w - 2.0f * (c2.x * p.x + c2.y * p.y + c2.z * p.z), 1e-12f));
        float d3 = sqrtf(fmaxf(c3.w + p.w - 2.0f * (c3.x * p.x + c3.y * p.y + c3.z * p.z), 1e-12f));
        if (d0 < RADIUS) {
            int p0 = atomicAdd(&cnt[0], 1);
            if (p0 < CAND) cand[0][p0] = (((unsigned long long)__float_as_uint(d0)) << 32) | (unsigned)n;
        }
        if (d1 < RADIUS) {
            int p1 = atomicAdd(&cnt[1], 1);
            if (p1 < CAND) cand[1][p1] = (((unsigned long long)__float_as_uint(d1)) << 32) | (unsigned)n;
        }
        if (d2 < RADIUS) {
            int p2 = atomicAdd(&cnt[2], 1);
            if (p2 < CAND) cand[2][p2] = (((unsigned long long)__float_as_uint(d2)) << 32) | (unsigned)n;
        }
        if (d3 < RADIUS) {
            int p3 = atomicAdd(&cnt[3], 1);
            if (p3 < CAND) cand[3][p3] = (((unsigned long long)__float_as_uint(d3)) << 32) | (unsigned)n;
        }
    }
    __syncthreads();
    int w = t >> 6, lane = t & 63;  // wave w extracts center m0+w
    int C = cnt[w] < CAND ? cnt[w] : CAND;
    volatile unsigned long long* vc = cand[w];
    for (int kit = 0; kit < KNBR; ++kit) {
        unsigned long long best = ~0ull;
        for (int i = lane; i < C; i += 64) {
            unsigned long long v = vc[i];
            if (v < best) best = v;
        }
        for (int off = 32; off; off >>= 1) {
            unsigned long long o = __shfl_xor(best, off);
            if (o < best) best = o;
        }
        for (int i = lane; i < C; i += 64)
            if (vc[i] == best) vc[i] = ~0ull;
        if (lane == 0) nbr[(m0 + w) * KNBR + kit] = (best == ~0ull) ? -1 : (int)(best & 0xffffffffu);
    }
}

// ---------------- kernel 3: attention + FFN, 8 centers per 256-thread block --
__global__ __launch_bounds__(256) void attn_ffn_kernel(
    const float* __restrict__ feats, const int* __restrict__ idxc,
    const int* __restrict__ nbr,
    const float* __restrict__ WqT, const float* __restrict__ Wk,
    const float* __restrict__ WvT, const float* __restrict__ WoT,
    const float* __restrict__ bo, const float* __restrict__ g1,
    const float* __restrict__ be1, const float* __restrict__ g2,
    const float* __restrict__ be2, const float* __restrict__ W1T,
    const float* __restrict__ b1f, const float* __restrict__ W2T,
    const float* __restrict__ b2f, float* __restrict__ cfin) {
    __shared__ __align__(16) float cf[CB][DIMF];
    __shared__ __align__(16) float cf2[CB][DIMF];
    __shared__ __align__(16) float S1[CB][4 * DIMF];  // qw -> pool -> h1
    __shared__ __align__(16) float S2[CB][DIMF];      // q -> updin
    __shared__ __align__(16) float S3[CB][DIMF];      // wsm -> upd -> ffn
    __shared__ int nbrl[CB][KNBR];

    int t = threadIdx.x;
    int m0 = blockIdx.x * CB;
    int lane127 = t & 127;
    int cg = (t >> 7) * 4;  // wave-uniform center group {0..3} or {4..7}
    int c8 = t >> 5, k32 = t & 31;

    // ---- load: cf rows + neighbor lists ----
    {
        int ic = idxc[m0 + c8];
        *(float4*)&cf[c8][k32 * 4] = *(const float4*)&feats[(long)ic * DIMF + k32 * 4];
        nbrl[c8][k32] = nbr[(m0 + c8) * KNBR + k32];
    }
    __syncthreads();

    // ---- A: q = Wq @ cf (scaled) -> S2 ----
    {
        float acc[4] = {0.f, 0.f, 0.f, 0.f};
        for (int jj = 0; jj < 32; ++jj) {
            float w0 = WqT[(jj * 4 + 0) * DIMF + lane127];
            float w1 = WqT[(jj * 4 + 1) * DIMF + lane127];
            float w2 = WqT[(jj * 4 + 2) * DIMF + lane127];
            float w3 = WqT[(jj * 4 + 3) * DIMF + lane127];
#pragma unroll
            for (int cc = 0; cc < 4; ++cc) {
                float4 x = *(const float4*)&cf[cg + cc][jj * 4];
                acc[cc] += w0 * x.x + w1 * x.y + w2 * x.z + w3 * x.w;
            }
        }
#pragma unroll
        for (int cc = 0; cc < 4; ++cc) S2[cg + cc][lane127] = acc[cc] * 0.17677669529663687f;
    }
    __syncthreads();

    // ---- B: qw[c][h][j] = sum_d q[c][h*32+d] * Wk[(h*32+d)*128+j] -> S1 ----
    {
        int j = lane127, hs = t >> 7;
#pragma unroll
        for (int hh = 0; hh < 2; ++hh) {
            int h = hs * 2 + hh;
            float acc[8] = {0.f, 0.f, 0.f, 0.f, 0.f, 0.f, 0.f, 0.f};
            for (int d4 = 0; d4 < 8; ++d4) {
                float w0 = Wk[(long)(h * DH + d4 * 4 + 0) * DIMF + j];
                float w1 = Wk[(long)(h * DH + d4 * 4 + 1) * DIMF + j];
                float w2 = Wk[(long)(h * DH + d4 * 4 + 2) * DIMF + j];
                float w3 = Wk[(long)(h * DH + d4 * 4 + 3) * DIMF + j];
#pragma unroll
                for (int c = 0; c < 8; ++c) {
                    float4 qv = *(const float4*)&S2[c][h * DH + d4 * 4];
                    acc[c] += qv.x * w0 + qv.y * w1 + qv.z * w2 + qv.w * w3;
                }
            }
#pragma unroll
            for (int c = 0; c < 8; ++c) S1[c][h * DIMF + j] = acc[c];
        }
    }
    __syncthreads();

    // ---- C: logits + softmax -> S3 (wsm[c][h*32+k]) ----
    {
        int ni = nbrl[c8][k32];
        const float* nrow = feats + (long)(ni < 0 ? 0 : ni) * DIMF;
        float lg[4] = {0.f, 0.f, 0.f, 0.f};
        for (int jj = 0; jj < 32; ++jj) {
            float4 f = *(const float4*)&nrow[jj * 4];
#pragma unroll
            for (int h = 0; h < 4; ++h) {
                float4 qwv = *(const float4*)&S1[c8][h * DIMF + jj * 4];
                lg[h] += f.x * qwv.x + f.y * qwv.y + f.z * qwv.z + f.w * qwv.w;
            }
        }
        if (ni < 0) { lg[0] = -1e9f; lg[1] = -1e9f; lg[2] = -1e9f; lg[3] = -1e9f; }
#pragma unroll
        for (int h = 0; h < 4; ++h) {
            float mx = lg[h];
            for (int o = 16; o; o >>= 1) mx = fmaxf(mx, __shfl_xor(mx, o, 32));
            float e = expf(lg[h] - mx);
            float s = e;
            for (int o = 16; o; o >>= 1) s += __shfl_xor(s, o, 32);
            S3[c8][h * KNBR + k32] = e / s;
        }
    }
    __syncthreads();

    // ---- D: pool[c][h][j] = sum_k wsm * nf -> S1 (overwrite qw) ----
    {
        int j4 = k32 * 4;
        float a0x = 0.f, a0y = 0.f, a0z = 0.f, a0w = 0.f;
        float a1x = 0.f, a1y = 0.f, a1z = 0.f, a1w = 0.f;
        float a2x = 0.f, a2y = 0.f, a2z = 0.f, a2w = 0.f;
        float a3x = 0.f, a3y = 0.f, a3z = 0.f, a3w = 0.f;
        for (int k = 0; k < KNBR; ++k) {
            int ni = nbrl[c8][k];
            const float* nrow = feats + (long)(ni < 0 ? 0 : ni) * DIMF;
            float4 f = *(const float4*)&nrow[j4];
            float w0 = S3[c8][0 * KNBR + k], w1 = S3[c8][1 * KNBR + k];
            float w2 = S3[c8][2 * KNBR + k], w3 = S3[c8][3 * KNBR + k];
            a0x += w0 * f.x; a0y += w0 * f.y; a0z += w0 * f.z; a0w += w0 * f.w;
            a1x += w1 * f.x; a1y += w1 * f.y; a1z += w1 * f.z; a1w += w1 * f.w;
            a2x += w2 * f.x; a2y += w2 * f.y; a2z += w2 * f.z; a2w += w2 * f.w;
            a3x += w3 * f.x; a3y += w3 * f.y; a3z += w3 * f.z; a3w += w3 * f.w;
        }
        __syncthreads();  // qw reads done; now overwrite S1 with pool
        *(float4*)&S1[c8][0 * DIMF + j4] = make_float4(a0x, a0y, a0z, a0w);
        *(float4*)&S1[c8][1 * DIMF + j4] = make_float4(a1x, a1y, a1z, a1w);
        *(float4*)&S1[c8][2 * DIMF + j4] = make_float4(a2x, a2y, a2z, a2w);
        *(float4*)&S1[c8][3 * DIMF + j4] = make_float4(a3x, a3y, a3z, a3w);
    }
    __syncthreads();

    // ---- E: updin[c][i->d*4+h] = Wv[i] . pool[c][h(i)] -> S2 ----
    {
        int i = lane127, h = i >> 5, d = i & 31;
        float acc[4] = {0.f, 0.f, 0.f, 0.f};
        for (int jj = 0; jj < 32; ++jj) {
            float w0 = WvT[(jj * 4 + 0) * DIMF + i];
            float w1 = WvT[(jj * 4 + 1) * DIMF + i];
            float w2 = WvT[(jj * 4 + 2) * DIMF + i];
            float w3 = WvT[(jj * 4 + 3) * DIMF + i];
#pragma unroll
            for (int cc = 0; cc < 4; ++cc) {
                float4 pv = *(const float4*)&S1[cg + cc][h * DIMF + jj * 4];
                acc[cc] += w0 * pv.x + w1 * pv.y + w2 * pv.z + w3 * pv.w;
            }
        }
        __syncthreads();  // q reads (phase B) long done; safe to overwrite S2
#pragma unroll
        for (int cc = 0; cc < 4; ++cc) S2[cg + cc][d * NH + h] = acc[cc];
    }
    __syncthreads();

    // ---- F: upd = Wo @ updin + bo -> S3 (wsm dead) ----
    {
        int i = lane127;
        float acc[4] = {0.f, 0.f, 0.f, 0.f};
        for (int jj = 0; jj < 32; ++jj) {
            float w0 = WoT[(jj * 4 + 0) * DIMF + i];
            float w1 = WoT[(jj * 4 + 1) * DIMF + i];
            float w2 = WoT[(jj * 4 + 2) * DIMF + i];
            float w3 = WoT[(jj * 4 + 3) * DIMF + i];
#pragma unroll
            for (int cc = 0; cc < 4; ++cc) {
                float4 x = *(const float4*)&S2[cg + cc][jj * 4];
                acc[cc] += w0 * x.x + w1 * x.y + w2 * x.z + w3 * x.w;
            }
        }
        float b = bo[i];
        __syncthreads();
#pragma unroll
        for (int cc = 0; cc < 4; ++cc) S3[cg + cc][i] = acc[cc] + b;
    }
    __syncthreads();

    // ---- G: LN1 + residual -> cf2 ----
    {
        int i4 = k32 * 4;
        float4 u = *(const float4*)&S3[c8][i4];
        float s = ((u.x + u.y) + u.z) + u.w;
        for (int o = 16; o; o >>= 1) s += __shfl_xor(s, o, 32);
        float mu = s * (1.0f / DIMF);
        float d0 = u.x - mu, d1 = u.y - mu, d2 = u.z - mu, d3 = u.w - mu;
        float vs = ((d0 * d0 + d1 * d1) + d2 * d2) + d3 * d3;
        for (int o = 16; o; o >>= 1) vs += __shfl_xor(vs, o, 32);
        float rs = 1.0f / sqrtf(vs * (1.0f / DIMF) + 1e-5f);
        float4 g = *(const float4*)&g1[i4];
        float4 b = *(const float4*)&be1[i4];
        float4 base = *(const float4*)&cf[c8][i4];
        float4 r;
        r.x = base.x + d0 * rs * g.x + b.x;
        r.y = base.y + d1 * rs * g.y + b.y;
        r.z = base.z + d2 * rs * g.z + b.z;
        r.w = base.w + d3 * rs * g.w + b.w;
        *(float4*)&cf2[c8][i4] = r;
    }
    __syncthreads();

    // ---- H: FFN1 (relu(W1 @ cf2 + b1f)) -> S1 (pool dead) ----
    {
        int u0 = lane127;
        float acc[4][4];
#pragma unroll
        for (int p = 0; p < 4; ++p)
#pragma unroll
            for (int cc = 0; cc < 4; ++cc) acc[p][cc] = 0.f;
        for (int jj = 0; jj < 32; ++jj) {
            float4 x[4];
#pragma unroll
            for (int cc = 0; cc < 4; ++cc) x[cc] = *(const float4*)&cf2[cg + cc][jj * 4];
#pragma unroll
            for (int p = 0; p < 4; ++p) {
                int u = u0 + p * DIMF;
                float w0 = W1T[(long)(jj * 4 + 0) * (4 * DIMF) + u];
                float w1 = W1T[(long)(jj * 4 + 1) * (4 * DIMF) + u];
                float w2 = W1T[(long)(jj * 4 + 2) * (4 * DIMF) + u];
                float w3 = W1T[(long)(jj * 4 + 3) * (4 * DIMF) + u];
#pragma unroll
                for (int cc = 0; cc < 4; ++cc)
                    acc[p][cc] += w0 * x[cc].x + w1 * x[cc].y + w2 * x[cc].z + w3 * x[cc].w;
            }
        }
#pragma unroll
        for (int p = 0; p < 4; ++p) {
            float b = b1f[u0 + p * DIMF];
#pragma unroll
            for (int cc = 0; cc < 4; ++cc)
                S1[cg + cc][u0 + p * DIMF] = fmaxf(acc[p][cc] + b, 0.f);
        }
    }
    __syncthreads();

    // ---- I: FFN2 (W2 @ h1 + b2f) -> S3 (upd dead) ----
    {
        int i = lane127;
        float acc[4] = {0.f, 0.f, 0.f, 0.f};
        for (int uu = 0; uu < 128; ++uu) {
            float w0 = W2T[(long)(uu * 4 + 0) * DIMF + i];
            float w1 = W2T[(long)(uu * 4 + 1) * DIMF + i];
            float w2 = W2T[(long)(uu * 4 + 2) * DIMF + i];
            float w3 = W2T[(long)(uu * 4 + 3) * DIMF + i];
#pragma unroll
            for (int cc = 0; cc < 4; ++cc) {
                float4 hh = *(const float4*)&S1[cg + cc][uu * 4];
                acc[cc] += w0 * hh.x + w1 * hh.y + w2 * hh.z + w3 * hh.w;
            }
        }
        float b = b2f[i];
        __syncthreads();
#pragma unroll
        for (int cc = 0; cc < 4; ++cc) S3[cg + cc][i] = acc[cc] + b;
    }
    __syncthreads();

    // ---- J: LN2 + residual -> cfin (global) ----
    {
        int i4 = k32 * 4;
        float4 u = *(const float4*)&S3[c8][i4];
        float s = ((u.x + u.y) + u.z) + u.w;
        for (int o = 16; o; o >>= 1) s += __shfl_xor(s, o, 32);
        float mu = s * (1.0f / DIMF);
        float d0 = u.x - mu, d1 = u.y - mu, d2 = u.z - mu, d3 = u.w - mu;
        float vs = ((d0 * d0 + d1 * d1) + d2 * d2) + d3 * d3;
        for (int o = 16; o; o >>= 1) vs += __shfl_xor(vs, o, 32);
        float rs = 1.0f / sqrtf(vs * (1.0f / DIMF) + 1e-5f);
        float4 g = *(const float4*)&g2[i4];
        float4 b = *(const float4*)&be2[i4];
        float4 base = *(const float4*)&cf2[c8][i4];
        float4 r;
        r.x = base.x + d0 * rs * g.x + b.x;
        r.y = base.y + d1 * rs * g.y + b.y;
        r.z = base.z + d2 * rs * g.z + b.z;
        r.w = base.w + d3 * rs * g.w + b.w;
        *(float4*)&cfin[(long)(m0 + c8) * DIMF + i4] = r;
    }
}

// ---------------- kernel 4a: init packed argmin ----------------
__global__ __launch_bounds__(256) void initpack_kernel(unsigned long long* __restrict__ p, int N) {
    int n = blockIdx.x * 256 + threadIdx.x;
    if (n < N) p[n] = ~0ull;
}

// ---------------- kernel 4b: nearest center via packed u64 atomicMin --------
__global__ __launch_bounds__(256) void nearest_kernel(const float4* __restrict__ pdata,
                                                      const float4* __restrict__ cdata,
                                                      unsigned long long* __restrict__ npack,
                                                      int N, int M) {
    __shared__ float4 cds[CT];
    int c0 = blockIdx.y * CT;
    int tile = (M - c0) < CT ? (M - c0) : CT;
    for (int i = threadIdx.x; i < tile; i += 256) cds[i] = cdata[c0 + i];
    __syncthreads();
    int n = blockIdx.x * 256 + threadIdx.x;
    if (n >= N) return;
    float4 p = pdata[n];
    unsigned long long best = ~0ull;
    for (int i = 0; i < tile; ++i) {
        float4 c = cds[i];
        float d2 = c.w + p.w - 2.0f * (c.x * p.x + c.y * p.y + c.z * p.z);
        float dist = sqrtf(fmaxf(d2, 1e-12f));
        unsigned long long pk = (((unsigned long long)__float_as_uint(dist)) << 32) | (unsigned)(c0 + i);
        if (pk < best) best = pk;
    }
    atomicMin(&npack[n], best);
}

// ---------------- kernel 5: out = feats + cfin[nearest] ----------------
__global__ __launch_bounds__(256) void out_kernel(const float4* __restrict__ feats4,
                                                  const float* __restrict__ cfin,
                                                  const unsigned long long* __restrict__ npack,
                                                  float4* __restrict__ out4, int total) {
    int idx = blockIdx.x * 256 + threadIdx.x;
    if (idx >= total) return;
    int n = idx >> 5, c = idx & 31;
    int m = (int)(npack[n] & 0xffffffffu);
    const float4* cf4 = (const float4*)cfin;
    float4 f = feats4[idx];
    float4 g = cf4[(long)m * 32 + c];
    out4[idx] = make_float4(f.x + g.x, f.y + g.y, f.z + g.z, f.w + g.w);
}

extern "C" void kernel_launch(void* const* d_in, const int* in_sizes, int n_in,
                              void* d_out, int out_size, void* d_ws, size_t ws_size,
                              hipStream_t stream) {
    const float* xyz = (const float*)d_in[0];
    const float* feats = (const float*)d_in[1];
    const int* idxc = (const int*)d_in[2];
    const float* Wq = (const float*)d_in[3];
    const float* Wk = (const float*)d_in[4];
    const float* Wv = (const float*)d_in[5];
    const float* Wo = (const float*)d_in[6];
    const float* bo = (const float*)d_in[7];
    const float* g1 = (const float*)d_in[8];
    const float* be1 = (const float*)d_in[9];
    const float* g2 = (const float*)d_in[10];
    const float* be2 = (const float*)d_in[11];
    const float* W1 = (const float*)d_in[12];
    const float* b1f = (const float*)d_in[13];
    const float* W2 = (const float*)d_in[14];
    const float* b2f = (const float*)d_in[15];

    int N = in_sizes[0] / 3;
    int M = in_sizes[2];

    char* ws = (char*)d_ws;
    size_t off = 0;
    float4* pdata = (float4*)(ws + off); off += (size_t)N * 16;
    float4* cdata = (float4*)(ws + off); off += (size_t)M * 16;
    int* nbr = (int*)(ws + off); off += (size_t)M * KNBR * 4;
    float* cfin = (float*)(ws + off); off += (size_t)M * DIMF * 4;
    unsigned long long* npack = (unsigned long long*)(ws + off); off += (size_t)N * 8;
    float* WqT = (float*)(ws + off); off += (size_t)DIMF * DIMF * 4;
    float* WvT = (float*)(ws + off); off += (size_t)DIMF * DIMF * 4;
    float* WoT = (float*)(ws + off); off += (size_t)DIMF * DIMF * 4;
    float* W1T = (float*)(ws + off); off += (size_t)4 * DIMF * DIMF * 4;
    float* W2T = (float*)(ws + off); off += (size_t)4 * DIMF * DIMF * 4;
    (void)ws_size; (void)n_in; (void)out_size;

    pdata_kernel<<<(N + 255) / 256, 256, 0, stream>>>(xyz, pdata, N);
    gather_kernel<<<(M + 255) / 256, 256, 0, stream>>>(pdata, idxc, cdata, M);

    dim3 tb(32, 8);
    transpose_kernel<<<dim3(4, 4), tb, 0, stream>>>(Wq, WqT, DIMF, DIMF);
    transpose_kernel<<<dim3(4, 4), tb, 0, stream>>>(Wv, WvT, DIMF, DIMF);
    transpose_kernel<<<dim3(4, 4), tb, 0, stream>>>(Wo, WoT, DIMF, DIMF);
    transpose_kernel<<<dim3(4, 16), tb, 0, stream>>>(W1, W1T, 4 * DIMF, DIMF);   // 512x128 -> 128x512
    transpose_kernel<<<dim3(16, 4), tb, 0, stream>>>(W2, W2T, DIMF, 4 * DIMF);   // 128x512 -> 512x128

    topk_kernel<<<M / TC, 256, 0, stream>>>(pdata, cdata, nbr, N);
    attn_ffn_kernel<<<M / CB, 256, 0, stream>>>(feats, idxc, nbr, WqT, Wk, WvT, WoT, bo,
                                                g1, be1, g2, be2, W1T, b1f, W2T, b2f, cfin);
    initpack_kernel<<<(N + 255) / 256, 256, 0, stream>>>(npack, N);
    nearest_kernel<<<dim3((N + 255) / 256, (M + CT - 1) / CT), 256, 0, stream>>>(pdata, cdata, npack, N, M);
    out_kernel<<<(N * DIMF / 4 + 255) / 256, 256, 0, stream>>>(
        (const float4*)feats, cfin, npack, (float4*)d_out, N * DIMF / 4);
}

// Round 3
// 241.159 us; speedup vs baseline: 3.6241x; 1.2624x over previous
//
#include <hip/hip_runtime.h>
#include <hip/hip_bf16.h>

#define DIMF 128
#define KNBR 32
#define NH 4
#define DH 32
#define RADIUS 0.3f
#define CB 8       // centers per attn block
#define TC 4       // centers per topk block
#define CAND 320   // max candidates/center (Poisson max ~117, 5-sigma ~172)
#define CT 256     // center tile in nearest

typedef unsigned long long u64t;

// ---------------- kernel 1: pack (x,y,z,|p|^2) + init npack ----------------
__global__ __launch_bounds__(256) void pdata_kernel(const float* __restrict__ xyz,
                                                    float4* __restrict__ pdata,
                                                    u64t* __restrict__ npack, int N) {
    int n = blockIdx.x * 256 + threadIdx.x;
    if (n < N) {
        float x = xyz[3 * n], y = xyz[3 * n + 1], z = xyz[3 * n + 2];
        pdata[n] = make_float4(x, y, z, (x * x + y * y) + z * z);
        npack[n] = ~0ull;
    }
}

// ---------------- kernel 1b: gather centers ----------------
__global__ __launch_bounds__(256) void gather_kernel(const float4* __restrict__ pdata,
                                                     const int* __restrict__ idxc,
                                                     float4* __restrict__ cdata, int M) {
    int m = blockIdx.x * 256 + threadIdx.x;
    if (m < M) cdata[m] = pdata[idxc[m]];
}

// ---------------- one launch: transpose all 5 weight matrices ----------------
__global__ void transpose_all(const float* __restrict__ Wq, const float* __restrict__ Wv,
                              const float* __restrict__ Wo, const float* __restrict__ W1,
                              const float* __restrict__ W2, float* __restrict__ WqT,
                              float* __restrict__ WvT, float* __restrict__ WoT,
                              float* __restrict__ W1T, float* __restrict__ W2T) {
    __shared__ float tile[32][33];
    const float* in;
    float* out;
    int R, C;
    switch (blockIdx.z) {
        case 0: in = Wq; out = WqT; R = 128; C = 128; break;
        case 1: in = Wv; out = WvT; R = 128; C = 128; break;
        case 2: in = Wo; out = WoT; R = 128; C = 128; break;
        case 3: in = W1; out = W1T; R = 512; C = 128; break;
        default: in = W2; out = W2T; R = 128; C = 512; break;
    }
    int bx = blockIdx.x * 32, by = blockIdx.y * 32;
    if (bx >= C || by >= R) return;
    int tx = threadIdx.x, ty = threadIdx.y;
    for (int r = ty; r < 32; r += 8) tile[r][tx] = in[(long)(by + r) * C + bx + tx];
    __syncthreads();
    for (int r = ty; r < 32; r += 8) out[(long)(bx + r) * R + by + tx] = tile[tx][r];
}

// ---------------- kernel 2: radius top-K, d2 keys + single-pass rank select --
__global__ __launch_bounds__(256) void topk_kernel(const float4* __restrict__ pdata,
                                                   const float4* __restrict__ cdata,
                                                   int* __restrict__ nbr, int N) {
    __shared__ u64t cand[TC][CAND];
    __shared__ int cnt[TC];
    int t = threadIdx.x;
    int m0 = blockIdx.x * TC;
    if (t < TC) cnt[t] = 0;
    __syncthreads();
    float nx[TC], ny[TC], nz[TC], cw[TC];
#pragma unroll
    for (int tc = 0; tc < TC; ++tc) {
        float4 c = cdata[m0 + tc];
        nx[tc] = -2.0f * c.x; ny[tc] = -2.0f * c.y; nz[tc] = -2.0f * c.z; cw[tc] = c.w;
    }
    const float R2 = RADIUS * RADIUS;
    for (int n = t; n < N; n += 256) {
        float4 p = pdata[n];
#pragma unroll
        for (int tc = 0; tc < TC; ++tc) {
            float d2 = fmaf(nx[tc], p.x, fmaf(ny[tc], p.y, fmaf(nz[tc], p.z, cw[tc] + p.w)));
            if (d2 < R2) {
                int pos = atomicAdd(&cnt[tc], 1);
                if (pos < CAND)
                    cand[tc][pos] = (((u64t)__float_as_uint(fmaxf(d2, 0.0f))) << 32) | (unsigned)n;
            }
        }
    }
    __syncthreads();
    // wave w handles center m0+w; keys are unique (index in low bits) ->
    // rank_i = #{j: key_j < key_i}; ranks 0..K-1 are exactly the K smallest.
    int w = t >> 6, lane = t & 63;
    int C = cnt[w] < CAND ? cnt[w] : CAND;
    const u64t* vc = cand[w];
    int* out = nbr + (m0 + w) * KNBR;
    if (C <= 64) {
        u64t mykey = (lane < C) ? vc[lane] : ~0ull;
        int rank = 0;
        for (int j = 0; j < C; ++j) rank += (vc[j] < mykey) ? 1 : 0;
        if (lane < C && rank < KNBR) out[rank] = (int)(mykey & 0xffffffffu);
        if (lane >= C && lane < KNBR) out[lane] = -1;  // C<K fill
    } else {
        u64t mykey[5];
        int myrank[5];
#pragma unroll
        for (int s = 0; s < 5; ++s) {
            int i = s * 64 + lane;
            mykey[s] = (i < C) ? vc[i] : ~0ull;
            myrank[s] = 0;
        }
        for (int j = 0; j < C; ++j) {
            u64t kj = vc[j];
#pragma unroll
            for (int s = 0; s < 5; ++s) myrank[s] += (kj < mykey[s]) ? 1 : 0;
        }
#pragma unroll
        for (int s = 0; s < 5; ++s) {
            int i = s * 64 + lane;
            if (i < C && myrank[s] < KNBR) out[myrank[s]] = (int)(mykey[s] & 0xffffffffu);
        }
    }
}

// ---------------- kernel 3: attention + FFN, 8 centers per 256-thread block --
__global__ __launch_bounds__(256) void attn_ffn_kernel(
    const float* __restrict__ feats, const int* __restrict__ idxc,
    const int* __restrict__ nbr,
    const float* __restrict__ WqT, const float* __restrict__ Wk,
    const float* __restrict__ WvT, const float* __restrict__ WoT,
    const float* __restrict__ bo, const float* __restrict__ g1,
    const float* __restrict__ be1, const float* __restrict__ g2,
    const float* __restrict__ be2, const float* __restrict__ W1T,
    const float* __restrict__ b1f, const float* __restrict__ W2T,
    const float* __restrict__ b2f, float* __restrict__ cfin) {
    __shared__ __align__(16) float cf[CB][DIMF];
    __shared__ __align__(16) float cf2[CB][DIMF];
    __shared__ __align__(16) float S1[CB][4 * DIMF];  // qw -> pool -> h1
    __shared__ __align__(16) float S2[CB][DIMF];      // q -> updin
    __shared__ __align__(16) float S3[CB][DIMF];      // wsm -> upd -> ffn
    __shared__ int nbrl[CB][KNBR];

    int t = threadIdx.x;
    int m0 = blockIdx.x * CB;
    int lane127 = t & 127;
    int cg = (t >> 7) * 4;  // wave-uniform center group {0..3} or {4..7}
    int c8 = t >> 5, k32 = t & 31;

    {
        int ic = idxc[m0 + c8];
        *(float4*)&cf[c8][k32 * 4] = *(const float4*)&feats[(long)ic * DIMF + k32 * 4];
        nbrl[c8][k32] = nbr[(m0 + c8) * KNBR + k32];
    }
    __syncthreads();

    // ---- A: q = Wq @ cf (scaled) -> S2 ----
    {
        float acc[4] = {0.f, 0.f, 0.f, 0.f};
        for (int jj = 0; jj < 32; ++jj) {
            float w0 = WqT[(jj * 4 + 0) * DIMF + lane127];
            float w1 = WqT[(jj * 4 + 1) * DIMF + lane127];
            float w2 = WqT[(jj * 4 + 2) * DIMF + lane127];
            float w3 = WqT[(jj * 4 + 3) * DIMF + lane127];
#pragma unroll
            for (int cc = 0; cc < 4; ++cc) {
                float4 x = *(const float4*)&cf[cg + cc][jj * 4];
                acc[cc] += w0 * x.x + w1 * x.y + w2 * x.z + w3 * x.w;
            }
        }
#pragma unroll
        for (int cc = 0; cc < 4; ++cc) S2[cg + cc][lane127] = acc[cc] * 0.17677669529663687f;
    }
    __syncthreads();

    // ---- B: qw[c][h][j] = sum_d q[c][h*32+d] * Wk[(h*32+d)*128+j] -> S1 ----
    {
        int j = lane127, hs = t >> 7;
#pragma unroll
        for (int hh = 0; hh < 2; ++hh) {
            int h = hs * 2 + hh;
            float acc[8] = {0.f, 0.f, 0.f, 0.f, 0.f, 0.f, 0.f, 0.f};
            for (int d4 = 0; d4 < 8; ++d4) {
                float w0 = Wk[(long)(h * DH + d4 * 4 + 0) * DIMF + j];
                float w1 = Wk[(long)(h * DH + d4 * 4 + 1) * DIMF + j];
                float w2 = Wk[(long)(h * DH + d4 * 4 + 2) * DIMF + j];
                float w3 = Wk[(long)(h * DH + d4 * 4 + 3) * DIMF + j];
#pragma unroll
                for (int c = 0; c < 8; ++c) {
                    float4 qv = *(const float4*)&S2[c][h * DH + d4 * 4];
                    acc[c] += qv.x * w0 + qv.y * w1 + qv.z * w2 + qv.w * w3;
                }
            }
#pragma unroll
            for (int c = 0; c < 8; ++c) S1[c][h * DIMF + j] = acc[c];
        }
    }
    __syncthreads();

    // ---- C: logits + softmax -> S3 (wsm[c][h*32+k]) ----
    {
        int ni = nbrl[c8][k32];
        const float* nrow = feats + (long)(ni < 0 ? 0 : ni) * DIMF;
        float lg[4] = {0.f, 0.f, 0.f, 0.f};
        for (int jj = 0; jj < 32; ++jj) {
            float4 f = *(const float4*)&nrow[jj * 4];
#pragma unroll
            for (int h = 0; h < 4; ++h) {
                float4 qwv = *(const float4*)&S1[c8][h * DIMF + jj * 4];
                lg[h] += f.x * qwv.x + f.y * qwv.y + f.z * qwv.z + f.w * qwv.w;
            }
        }
        if (ni < 0) { lg[0] = -1e9f; lg[1] = -1e9f; lg[2] = -1e9f; lg[3] = -1e9f; }
#pragma unroll
        for (int h = 0; h < 4; ++h) {
            float mx = lg[h];
            for (int o = 16; o; o >>= 1) mx = fmaxf(mx, __shfl_xor(mx, o, 32));
            float e = expf(lg[h] - mx);
            float s = e;
            for (int o = 16; o; o >>= 1) s += __shfl_xor(s, o, 32);
            S3[c8][h * KNBR + k32] = e / s;
        }
    }
    __syncthreads();

    // ---- D: pool[c][h][j] = sum_k wsm * nf -> S1 (overwrite qw) ----
    {
        int j4 = k32 * 4;
        float a0x = 0.f, a0y = 0.f, a0z = 0.f, a0w = 0.f;
        float a1x = 0.f, a1y = 0.f, a1z = 0.f, a1w = 0.f;
        float a2x = 0.f, a2y = 0.f, a2z = 0.f, a2w = 0.f;
        float a3x = 0.f, a3y = 0.f, a3z = 0.f, a3w = 0.f;
        for (int k = 0; k < KNBR; ++k) {
            int ni = nbrl[c8][k];
            const float* nrow = feats + (long)(ni < 0 ? 0 : ni) * DIMF;
            float4 f = *(const float4*)&nrow[j4];
            float w0 = S3[c8][0 * KNBR + k], w1 = S3[c8][1 * KNBR + k];
            float w2 = S3[c8][2 * KNBR + k], w3 = S3[c8][3 * KNBR + k];
            a0x += w0 * f.x; a0y += w0 * f.y; a0z += w0 * f.z; a0w += w0 * f.w;
            a1x += w1 * f.x; a1y += w1 * f.y; a1z += w1 * f.z; a1w += w1 * f.w;
            a2x += w2 * f.x; a2y += w2 * f.y; a2z += w2 * f.z; a2w += w2 * f.w;
            a3x += w3 * f.x; a3y += w3 * f.y; a3z += w3 * f.z; a3w += w3 * f.w;
        }
        __syncthreads();
        *(float4*)&S1[c8][0 * DIMF + j4] = make_float4(a0x, a0y, a0z, a0w);
        *(float4*)&S1[c8][1 * DIMF + j4] = make_float4(a1x, a1y, a1z, a1w);
        *(float4*)&S1[c8][2 * DIMF + j4] = make_float4(a2x, a2y, a2z, a2w);
        *(float4*)&S1[c8][3 * DIMF + j4] = make_float4(a3x, a3y, a3z, a3w);
    }
    __syncthreads();

    // ---- E: updin[c][i->d*4+h] = Wv[i] . pool[c][h(i)] -> S2 ----
    {
        int i = lane127, h = i >> 5, d = i & 31;
        float acc[4] = {0.f, 0.f, 0.f, 0.f};
        for (int jj = 0; jj < 32; ++jj) {
            float w0 = WvT[(jj * 4 + 0) * DIMF + i];
            float w1 = WvT[(jj * 4 + 1) * DIMF + i];
            float w2 = WvT[(jj * 4 + 2) * DIMF + i];
            float w3 = WvT[(jj * 4 + 3) * DIMF + i];
#pragma unroll
            for (int cc = 0; cc < 4; ++cc) {
                float4 pv = *(const float4*)&S1[cg + cc][h * DIMF + jj * 4];
                acc[cc] += w0 * pv.x + w1 * pv.y + w2 * pv.z + w3 * pv.w;
            }
        }
        __syncthreads();
#pragma unroll
        for (int cc = 0; cc < 4; ++cc) S2[cg + cc][d * NH + h] = acc[cc];
    }
    __syncthreads();

    // ---- F: upd = Wo @ updin + bo -> S3 ----
    {
        int i = lane127;
        float acc[4] = {0.f, 0.f, 0.f, 0.f};
        for (int jj = 0; jj < 32; ++jj) {
            float w0 = WoT[(jj * 4 + 0) * DIMF + i];
            float w1 = WoT[(jj * 4 + 1) * DIMF + i];
            float w2 = WoT[(jj * 4 + 2) * DIMF + i];
            float w3 = WoT[(jj * 4 + 3) * DIMF + i];
#pragma unroll
            for (int cc = 0; cc < 4; ++cc) {
                float4 x = *(const float4*)&S2[cg + cc][jj * 4];
                acc[cc] += w0 * x.x + w1 * x.y + w2 * x.z + w3 * x.w;
            }
        }
        float b = bo[i];
        __syncthreads();
#pragma unroll
        for (int cc = 0; cc < 4; ++cc) S3[cg + cc][i] = acc[cc] + b;
    }
    __syncthreads();

    // ---- G: LN1 + residual -> cf2 ----
    {
        int i4 = k32 * 4;
        float4 u = *(const float4*)&S3[c8][i4];
        float s = ((u.x + u.y) + u.z) + u.w;
        for (int o = 16; o; o >>= 1) s += __shfl_xor(s, o, 32);
        float mu = s * (1.0f / DIMF);
        float d0 = u.x - mu, d1 = u.y - mu, d2 = u.z - mu, d3 = u.w - mu;
        float vs = ((d0 * d0 + d1 * d1) + d2 * d2) + d3 * d3;
        for (int o = 16; o; o >>= 1) vs += __shfl_xor(vs, o, 32);
        float rs = 1.0f / sqrtf(vs * (1.0f / DIMF) + 1e-5f);
        float4 g = *(const float4*)&g1[i4];
        float4 b = *(const float4*)&be1[i4];
        float4 base = *(const float4*)&cf[c8][i4];
        float4 r;
        r.x = base.x + d0 * rs * g.x + b.x;
        r.y = base.y + d1 * rs * g.y + b.y;
        r.z = base.z + d2 * rs * g.z + b.z;
        r.w = base.w + d3 * rs * g.w + b.w;
        *(float4*)&cf2[c8][i4] = r;
    }
    __syncthreads();

    // ---- H: FFN1 (relu(W1 @ cf2 + b1f)) -> S1 ----
    {
        int u0 = lane127;
        float acc[4][4];
#pragma unroll
        for (int p = 0; p < 4; ++p)
#pragma unroll
            for (int cc = 0; cc < 4; ++cc) acc[p][cc] = 0.f;
        for (int jj = 0; jj < 32; ++jj) {
            float4 x[4];
#pragma unroll
            for (int cc = 0; cc < 4; ++cc) x[cc] = *(const float4*)&cf2[cg + cc][jj * 4];
#pragma unroll
            for (int p = 0; p < 4; ++p) {
                int u = u0 + p * DIMF;
                float w0 = W1T[(long)(jj * 4 + 0) * (4 * DIMF) + u];
                float w1 = W1T[(long)(jj * 4 + 1) * (4 * DIMF) + u];
                float w2 = W1T[(long)(jj * 4 + 2) * (4 * DIMF) + u];
                float w3 = W1T[(long)(jj * 4 + 3) * (4 * DIMF) + u];
#pragma unroll
                for (int cc = 0; cc < 4; ++cc)
                    acc[p][cc] += w0 * x[cc].x + w1 * x[cc].y + w2 * x[cc].z + w3 * x[cc].w;
            }
        }
#pragma unroll
        for (int p = 0; p < 4; ++p) {
            float b = b1f[u0 + p * DIMF];
#pragma unroll
            for (int cc = 0; cc < 4; ++cc)
                S1[cg + cc][u0 + p * DIMF] = fmaxf(acc[p][cc] + b, 0.f);
        }
    }
    __syncthreads();

    // ---- I: FFN2 (W2 @ h1 + b2f) -> S3 ----
    {
        int i = lane127;
        float acc[4] = {0.f, 0.f, 0.f, 0.f};
        for (int uu = 0; uu < 128; ++uu) {
            float w0 = W2T[(long)(uu * 4 + 0) * DIMF + i];
            float w1 = W2T[(long)(uu * 4 + 1) * DIMF + i];
            float w2 = W2T[(long)(uu * 4 + 2) * DIMF + i];
            float w3 = W2T[(long)(uu * 4 + 3) * DIMF + i];
#pragma unroll
            for (int cc = 0; cc < 4; ++cc) {
                float4 hh = *(const float4*)&S1[cg + cc][uu * 4];
                acc[cc] += w0 * hh.x + w1 * hh.y + w2 * hh.z + w3 * hh.w;
            }
        }
        float b = b2f[i];
        __syncthreads();
#pragma unroll
        for (int cc = 0; cc < 4; ++cc) S3[cg + cc][i] = acc[cc] + b;
    }
    __syncthreads();

    // ---- J: LN2 + residual -> cfin (global) ----
    {
        int i4 = k32 * 4;
        float4 u = *(const float4*)&S3[c8][i4];
        float s = ((u.x + u.y) + u.z) + u.w;
        for (int o = 16; o; o >>= 1) s += __shfl_xor(s, o, 32);
        float mu = s * (1.0f / DIMF);
        float d0 = u.x - mu, d1 = u.y - mu, d2 = u.z - mu, d3 = u.w - mu;
        float vs = ((d0 * d0 + d1 * d1) + d2 * d2) + d3 * d3;
        for (int o = 16; o; o >>= 1) vs += __shfl_xor(vs, o, 32);
        float rs = 1.0f / sqrtf(vs * (1.0f / DIMF) + 1e-5f);
        float4 g = *(const float4*)&g2[i4];
        float4 b = *(const float4*)&be2[i4];
        float4 base = *(const float4*)&cf2[c8][i4];
        float4 r;
        r.x = base.x + d0 * rs * g.x + b.x;
        r.y = base.y + d1 * rs * g.y + b.y;
        r.z = base.z + d2 * rs * g.z + b.z;
        r.w = base.w + d3 * rs * g.w + b.w;
        *(float4*)&cfin[(long)(m0 + c8) * DIMF + i4] = r;
    }
}

// ---------------- kernel 4: nearest center via packed u64 atomicMin ----------
__global__ __launch_bounds__(256) void nearest_kernel(const float4* __restrict__ pdata,
                                                      const float4* __restrict__ cdata,
                                                      u64t* __restrict__ npack,
                                                      int N, int M) {
    __shared__ float4 cds[CT];
    int c0 = blockIdx.y * CT;
    if (c0 + (int)threadIdx.x < M) cds[threadIdx.x] = cdata[c0 + threadIdx.x];
    __syncthreads();
    int n = blockIdx.x * 256 + threadIdx.x;
    if (n >= N) return;
    int tile = (M - c0) < CT ? (M - c0) : CT;
    float4 p = pdata[n];
    u64t best = ~0ull;
    for (int i = 0; i < tile; ++i) {
        float4 c = cds[i];
        float d2 = c.w + p.w - 2.0f * (c.x * p.x + c.y * p.y + c.z * p.z);
        float dist = sqrtf(fmaxf(d2, 1e-12f));  // keep ref tie semantics for argmin
        u64t pk = (((u64t)__float_as_uint(dist)) << 32) | (unsigned)(c0 + i);
        if (pk < best) best = pk;
    }
    atomicMin(&npack[n], best);
}

// ---------------- kernel 5: out = feats + cfin[nearest] ----------------
__global__ __launch_bounds__(256) void out_kernel(const float4* __restrict__ feats4,
                                                  const float* __restrict__ cfin,
                                                  const u64t* __restrict__ npack,
                                                  float4* __restrict__ out4, int total) {
    int idx = blockIdx.x * 256 + threadIdx.x;
    if (idx >= total) return;
    int n = idx >> 5, c = idx & 31;
    int m = (int)(npack[n] & 0xffffffffu);
    const float4* cf4 = (const float4*)cfin;
    float4 f = feats4[idx];
    float4 g = cf4[(long)m * 32 + c];
    out4[idx] = make_float4(f.x + g.x, f.y + g.y, f.z + g.z, f.w + g.w);
}

extern "C" void kernel_launch(void* const* d_in, const int* in_sizes, int n_in,
                              void* d_out, int out_size, void* d_ws, size_t ws_size,
                              hipStream_t stream) {
    const float* xyz = (const float*)d_in[0];
    const float* feats = (const float*)d_in[1];
    const int* idxc = (const int*)d_in[2];
    const float* Wq = (const float*)d_in[3];
    const float* Wk = (const float*)d_in[4];
    const float* Wv = (const float*)d_in[5];
    const float* Wo = (const float*)d_in[6];
    const float* bo = (const float*)d_in[7];
    const float* g1 = (const float*)d_in[8];
    const float* be1 = (const float*)d_in[9];
    const float* g2 = (const float*)d_in[10];
    const float* be2 = (const float*)d_in[11];
    const float* W1 = (const float*)d_in[12];
    const float* b1f = (const float*)d_in[13];
    const float* W2 = (const float*)d_in[14];
    const float* b2f = (const float*)d_in[15];

    int N = in_sizes[0] / 3;
    int M = in_sizes[2];

    char* ws = (char*)d_ws;
    size_t off = 0;
    float4* pdata = (float4*)(ws + off); off += (size_t)N * 16;
    float4* cdata = (float4*)(ws + off); off += (size_t)M * 16;
    int* nbr = (int*)(ws + off); off += (size_t)M * KNBR * 4;
    float* cfin = (float*)(ws + off); off += (size_t)M * DIMF * 4;
    u64t* npack = (u64t*)(ws + off); off += (size_t)N * 8;
    float* WqT = (float*)(ws + off); off += (size_t)DIMF * DIMF * 4;
    float* WvT = (float*)(ws + off); off += (size_t)DIMF * DIMF * 4;
    float* WoT = (float*)(ws + off); off += (size_t)DIMF * DIMF * 4;
    float* W1T = (float*)(ws + off); off += (size_t)4 * DIMF * DIMF * 4;
    float* W2T = (float*)(ws + off); off += (size_t)4 * DIMF * DIMF * 4;
    (void)ws_size; (void)n_in; (void)out_size;

    pdata_kernel<<<(N + 255) / 256, 256, 0, stream>>>(xyz, pdata, npack, N);
    gather_kernel<<<(M + 255) / 256, 256, 0, stream>>>(pdata, idxc, cdata, M);
    transpose_all<<<dim3(16, 16, 5), dim3(32, 8), 0, stream>>>(Wq, Wv, Wo, W1, W2,
                                                               WqT, WvT, WoT, W1T, W2T);
    topk_kernel<<<M / TC, 256, 0, stream>>>(pdata, cdata, nbr, N);
    attn_ffn_kernel<<<M / CB, 256, 0, stream>>>(feats, idxc, nbr, WqT, Wk, WvT, WoT, bo,
                                                g1, be1, g2, be2, W1T, b1f, W2T, b2f, cfin);
    nearest_kernel<<<dim3((N + 255) / 256, (M + CT - 1) / CT), 256, 0, stream>>>(pdata, cdata, npack, N, M);
    out_kernel<<<(N * DIMF / 4 + 255) / 256, 256, 0, stream>>>(
        (const float4*)feats, cfin, npack, (float4*)d_out, N * DIMF / 4);
}